// Round 11
// baseline (13643.707 us; speedup 1.0000x reference)
//
#include <hip/hip_runtime.h>
#include <stdint.h>

// Problem dims
#define BB 32
#define SS 2048
#define II 128
#define HH 512
#define OO 128

// Block roles: 16 layer-0 blocks (32 units, 4 waves full-K),
// 32 layer-1 blocks (16 units, 4 waves split-K), 4 Y blocks (32 out cols).
#define N0 16
#define N1 32
#define NYB 4
#define NBLK (N0 + N1 + NYB)      // 52
#define THREADS 256

// Workspace:
//  f0w[64]  @0    : role0 wave flags. f0=p  <=> wave validated h0(p-1) reads.
//  f1a[64]  @256  : role1 kh0 wave flags. =q <=> validated h0(q-1) reads.
//  f1b[64]  @512  : role1 kh1 wave flags. =q <=> validated h1(q-2) reads.
//  fy[16]   @768  : Y wave flags. =p <=> validated h1(p-2) reads.
//  pub0 u32[4][32][512] @4096, pub1 same @4096+256KB. Word = (bf16<<16)|tag.
//  Tags: h0(p) tag p+1 slot p&3; h1(k) tag k+1 slot k&3. Tags <= 2049 < 2^16.
//  Tag-in-data: the store IS the signal (no producer drain, no flag hop).
//  AND-fold sound: stale tag s<t can't give (AND==t); future tags excluded by
//  guards (writer@P blocked until readers' validated-flags >= P-3); memset
//  (tag 0) NEVER read (p=0 / q=1 skip h-chunks; h(-1)=0 handled in-register).
#define F0W_OFF 0
#define F1A_OFF 256
#define F1B_OFF 512
#define FY_OFF  768
#define SLOT_W  (BB * HH)                   // u32 words per slot (16384)
#define PUB0_OFF 4096
#define PUB1_OFF (4096 + 4 * SLOT_W * 4)    // +256KB
#define WS_BYTES (4096 + 2 * 4 * SLOT_W * 4)  // 528KB (proven footprint)

// LDS: role0 120KB weights; role1 96KB weights + 12KB parity-dbuf reduce.
#define REDOFF    98304
#define LDS_BYTES (120 * 1024)

typedef __attribute__((ext_vector_type(8))) short short8;   // 8 x bf16
typedef __attribute__((ext_vector_type(4))) float f32x4;
typedef __attribute__((ext_vector_type(4))) unsigned int u32x4;

__device__ __forceinline__ short f2bf(float f) {
  unsigned int u = __float_as_uint(f);
  u += 0x7fffu + ((u >> 16) & 1u);        // RNE
  return (short)(u >> 16);
}
__device__ __forceinline__ float sigm(float v) { return 1.0f / (1.0f + __expf(-v)); }
__device__ __forceinline__ float tanhc(float v) {
  v = fminf(fmaxf(v, -15.0f), 15.0f);
  float e = __expf(2.0f * v);
  return (e - 1.0f) / (e + 1.0f);
}

// Agent-scope L1/L2-bypass accesses (sc1): R6/R10-proven coherence semantics.
#define LDG4T(dst_, p_) asm volatile("global_load_dwordx4 %0, %1, off sc1" : "=&v"(dst_) : "v"(p_))
#define LDGU(dst_, p_)  asm volatile("global_load_dword %0, %1, off sc1" : "=&v"(dst_) : "v"(p_))
#define STG4(p_, v_)    asm volatile("global_store_dword %0, %1, off sc1" :: "v"(p_), "v"(v_))
#define VDRAIN() do { \
  asm volatile("s_waitcnt vmcnt(0)" ::: "memory"); \
  __builtin_amdgcn_sched_barrier(0); \
} while (0)

// 8 tagged u32 -> 8 bf16 (high halves)
__device__ __forceinline__ short8 mk_afT(u32x4 a, u32x4 b) {
  short8 r;
  r[0] = (short)(a[0] >> 16); r[1] = (short)(a[1] >> 16);
  r[2] = (short)(a[2] >> 16); r[3] = (short)(a[3] >> 16);
  r[4] = (short)(b[0] >> 16); r[5] = (short)(b[1] >> 16);
  r[6] = (short)(b[2] >> 16); r[7] = (short)(b[3] >> 16);
  return r;
}
__device__ __forceinline__ short8 mk_af_x(float4 a, float4 b) {
  short8 r;
  r[0] = f2bf(a.x); r[1] = f2bf(a.y); r[2] = f2bf(a.z); r[3] = f2bf(a.w);
  r[4] = f2bf(b.x); r[5] = f2bf(b.y); r[6] = f2bf(b.z); r[7] = f2bf(b.w);
  return r;
}

// One chunk = 8 k-tiles = 16 dwordx4 = 64 VGPRs in flight (R6-proven cap).
// issue -> IMMEDIATE VDRAIN -> check, nothing in between (in-flight asm-output
// regs must never cross other code: the compiler may copy/spill them before
// the load lands -> garbage -> infinite spin; this was the R7/R8 hang).
// Whole-chunk retry, no partial masks, no sleep (R10: backoff-free poll ok).
__device__ __forceinline__ void chunk_wait(const unsigned int* base, int k0,
                                           unsigned tag, u32x4* pw) {
  for (;;) {
#pragma unroll
    for (int i = 0; i < 8; ++i) {
      LDG4T(pw[2 * i],     base + (k0 + i) * 32);
      LDG4T(pw[2 * i + 1], base + (k0 + i) * 32 + 4);
    }
    VDRAIN();
    unsigned a = 0xFFFFFFFFu;
#pragma unroll
    for (int i = 0; i < 16; ++i) a &= pw[i][0] & pw[i][1] & pw[i][2] & pw[i][3];
    if (__all((int)((a & 0xFFFFu) == tag))) return;
  }
}

__global__ __launch_bounds__(THREADS, 1)
void gru_persist(const float* __restrict__ x,
                 const float* __restrict__ wx0, const float* __restrict__ bx0,
                 const float* __restrict__ wh0,
                 const float* __restrict__ wx1, const float* __restrict__ bx1,
                 const float* __restrict__ wh1,
                 const float* __restrict__ wy,  const float* __restrict__ by,
                 float* __restrict__ out, unsigned char* __restrict__ ws)
{
  extern __shared__ char smem[];
  short8* ldsw = (short8*)smem;                 // weight frags: frag f at ldsw[(f<<6)+lane]
  float*  red  = (float*)(smem + REDOFF);       // role1 split-K reduce (parity dbuf)

  unsigned int* f0w  = (unsigned int*)(ws + F0W_OFF);
  unsigned int* f1a  = (unsigned int*)(ws + F1A_OFF);
  unsigned int* f1b  = (unsigned int*)(ws + F1B_OFF);
  unsigned int* fyf  = (unsigned int*)(ws + FY_OFF);
  unsigned int* pub0 = (unsigned int*)(ws + PUB0_OFF);
  unsigned int* pub1 = (unsigned int*)(ws + PUB1_OFF);

  const int tid = threadIdx.x;
  const int l   = tid & 63;
  const int wv  = tid >> 6;
  const int lr  = l & 15;
  const int lg  = l >> 4;
  const int bid = blockIdx.x;
  const int role = (bid < N0) ? 0 : (bid < N0 + N1) ? 1 : 2;

  // ---------- one-time weight preload into LDS, MFMA B-fragment order ----------
  if (role == 0) {
    for (int f = wv; f < 120; f += 4) {         // [uh(2)][gate(3)][kt(20)]
      const int uh = f / 60, g = (f % 60) / 20, kt = f % 20;
      const int row = g * 512 + bid * 32 + uh * 16 + lr;
      const float* src = (kt < 4) ? (wx0 + (size_t)row * II + kt * 32 + lg * 8)
                                  : (wh0 + (size_t)row * HH + (kt - 4) * 32 + lg * 8);
      short8 v;
#pragma unroll
      for (int j = 0; j < 8; ++j) v[j] = f2bf(src[j]);
      ldsw[(f << 6) + l] = v;
    }
  } else if (role == 1) {
    const int ub = (bid - N0) * 16;
    for (int f = wv; f < 96; f += 4) {          // [gate(3)][kt(32)]: kt<16 h0-side, else h1-side
      const int g = f >> 5, kt = f & 31;
      const int row = g * 512 + ub + lr;
      const float* src = (kt < 16) ? (wx1 + (size_t)row * HH + kt * 32 + lg * 8)
                                   : (wh1 + (size_t)row * HH + (kt - 16) * 32 + lg * 8);
      short8 v;
#pragma unroll
      for (int j = 0; j < 8; ++j) v[j] = f2bf(src[j]);
      ldsw[(f << 6) + l] = v;
    }
  } else {
    const int oy = (bid - N0 - N1) * 32;
    for (int f = wv; f < 32; f += 4) {          // [nt(2)][kt(16)]
      const int nt = f >> 4, kt = f & 15;
      const int row = oy + nt * 16 + lr;
      const float* src = wy + (size_t)row * HH + kt * 32 + lg * 8;
      short8 v;
#pragma unroll
      for (int j = 0; j < 8; ++j) v[j] = f2bf(src[j]);
      ldsw[(f << 6) + l] = v;
    }
  }
  __syncthreads();

  if (role == 0) {
    // wave (mh, uh): 16 batch rows x 16 units, full K=640. NO barriers in loop.
    const int mh  = wv & 1;
    const int uh  = wv >> 1;
    const int bA  = mh * 16 + lr;
    const int bC  = mh * 16 + lg * 4;
    const int u0w = bid * 32 + uh * 16;
    const int fb  = uh * 60;
    const float bz = bx0[u0w + lr], br = bx0[512 + u0w + lr], bg = bx0[1024 + u0w + lr];
    unsigned int* myf = f0w + bid * 4 + wv;
    f32x4 hm = {0.f, 0.f, 0.f, 0.f};
    u32x4 pw[16];

    for (int p = 0; p < SS; ++p) {
      // guard pre-loads (drained by chunk VDRAIN; stale = stricter, values grow)
      unsigned gf0, gf1;
      LDGU(gf0, f0w + l);
      LDGU(gf1, f1a + l);
      // x loads (cached, immutable)
      const float* xp = x + (size_t)bA * (SS * II) + (size_t)p * II + lg * 8;
      float4 xa[4], xb[4];
#pragma unroll
      for (int t = 0; t < 4; ++t) {
        xa[t] = *(const float4*)(xp + t * 32);
        xb[t] = *(const float4*)(xp + t * 32 + 4);
      }
      f32x4 aZ = {0,0,0,0}, aR = {0,0,0,0}, aG1 = {0,0,0,0}, aG2 = {0,0,0,0};
      if (p > 0) {
        // h0(p-1): tag-in-data poll, two sequential 8-kt chunks
        const unsigned int* pbase = pub0 + (size_t)((p - 1) & 3) * SLOT_W + bA * 512 + lg * 8;
        chunk_wait(pbase, 0, (unsigned)p, pw);
#pragma unroll
        for (int i = 0; i < 8; ++i) {
          short8 af = mk_afT(pw[2 * i], pw[2 * i + 1]);
          aZ  = __builtin_amdgcn_mfma_f32_16x16x32_bf16(af, ldsw[((fb + 4 + i) << 6) + l], aZ, 0, 0, 0);
          aR  = __builtin_amdgcn_mfma_f32_16x16x32_bf16(af, ldsw[((fb + 24 + i) << 6) + l], aR, 0, 0, 0);
          aG2 = __builtin_amdgcn_mfma_f32_16x16x32_bf16(af, ldsw[((fb + 44 + i) << 6) + l], aG2, 0, 0, 0);
        }
        chunk_wait(pbase, 8, (unsigned)p, pw);
#pragma unroll
        for (int i = 0; i < 8; ++i) {
          short8 af = mk_afT(pw[2 * i], pw[2 * i + 1]);
          aZ  = __builtin_amdgcn_mfma_f32_16x16x32_bf16(af, ldsw[((fb + 12 + i) << 6) + l], aZ, 0, 0, 0);
          aR  = __builtin_amdgcn_mfma_f32_16x16x32_bf16(af, ldsw[((fb + 32 + i) << 6) + l], aR, 0, 0, 0);
          aG2 = __builtin_amdgcn_mfma_f32_16x16x32_bf16(af, ldsw[((fb + 52 + i) << 6) + l], aG2, 0, 0, 0);
        }
        if (l == 0) STG4(myf, (unsigned)p);      // validated h0(p-1): fire & forget
      }
      // x-part MFMAs
#pragma unroll
      for (int kt = 0; kt < 4; ++kt) {
        short8 af = mk_af_x(xa[kt], xb[kt]);
        aZ  = __builtin_amdgcn_mfma_f32_16x16x32_bf16(af, ldsw[((fb + kt) << 6) + l], aZ, 0, 0, 0);
        aR  = __builtin_amdgcn_mfma_f32_16x16x32_bf16(af, ldsw[((fb + 20 + kt) << 6) + l], aR, 0, 0, 0);
        aG1 = __builtin_amdgcn_mfma_f32_16x16x32_bf16(af, ldsw[((fb + 40 + kt) << 6) + l], aG1, 0, 0, 0);
      }
      // overwrite guard: slot p&3 clobbers h0(p-4); readers validated at phase p-3
      if (p >= 4) {
        const unsigned thr = (unsigned)(p - 3);
        while (!__all((int)((gf0 >= thr) & (gf1 >= thr)))) {
          __builtin_amdgcn_s_sleep(2);
          LDGU(gf0, f0w + l);
          LDGU(gf1, f1a + l);
          VDRAIN();
        }
      }
      // gates + tagged publish (fire & forget; the tag IS the flag)
      unsigned int* po = pub0 + (size_t)(p & 3) * SLOT_W + u0w + lr;
      const unsigned tagO = (unsigned)(p + 1);
#pragma unroll
      for (int r = 0; r < 4; ++r) {
        const float zz = sigm(aZ[r] + bz);
        const float rr = sigm(aR[r] + br);
        const float gg = tanhc(aG1[r] + bg + rr * aG2[r]);
        const float hn = gg + zz * (hm[r] - gg);
        hm[r] = hn;
        STG4(po + (size_t)(bC + r) * 512, ((unsigned)(unsigned short)f2bf(hn) << 16) | tagO);
        if (p == SS - 1)
          out[(size_t)(BB * SS * OO) + (size_t)(bC + r) * (2 * HH) + u0w + lr] = hn;
      }
    }
  } else if (role == 1) {
    // waves (mh, kh): split-K. kh0 = h0(q-1) side (kt 0..15, gate-x aG1) + publish;
    // kh1 = h1(q-2) side (kt 16..31 -> partials to red). ONE barrier/iteration.
    const int mh = wv & 1;
    const int kh = wv >> 1;
    const int bA = mh * 16 + lr;
    const int bC = mh * 16 + lg * 4;
    const int u0 = (bid - N0) * 16;
    float bz = 0.f, br = 0.f, bg = 0.f;
    if (kh == 0) { bz = bx1[u0 + lr]; br = bx1[512 + u0 + lr]; bg = bx1[1024 + u0 + lr]; }
    unsigned int* myfa = f1a + (bid - N0) * 2 + mh;
    unsigned int* myfb = f1b + (bid - N0) * 2 + mh;
    f32x4 hm = {0.f, 0.f, 0.f, 0.f};
    u32x4 pw[16];

    for (int q = 1; q <= SS; ++q) {
      const int par = q & 1;
      f32x4 aZ = {0,0,0,0}, aR = {0,0,0,0}, aG1 = {0,0,0,0}, aG2 = {0,0,0,0};
      unsigned gfb, gfy;
      if (kh == 1) {
        if (q >= 2) {                            // q==1: h1(-1)=0, nothing to read
          const unsigned int* b1 = pub1 + (size_t)((q - 2) & 3) * SLOT_W + bA * 512 + lg * 8;
          chunk_wait(b1, 0, (unsigned)(q - 1), pw);
#pragma unroll
          for (int i = 0; i < 8; ++i) {
            const int kt = 16 + i;
            short8 af = mk_afT(pw[2 * i], pw[2 * i + 1]);
            aZ  = __builtin_amdgcn_mfma_f32_16x16x32_bf16(af, ldsw[((0 * 32 + kt) << 6) + l], aZ, 0, 0, 0);
            aR  = __builtin_amdgcn_mfma_f32_16x16x32_bf16(af, ldsw[((1 * 32 + kt) << 6) + l], aR, 0, 0, 0);
            aG2 = __builtin_amdgcn_mfma_f32_16x16x32_bf16(af, ldsw[((2 * 32 + kt) << 6) + l], aG2, 0, 0, 0);
          }
          chunk_wait(b1, 8, (unsigned)(q - 1), pw);
#pragma unroll
          for (int i = 0; i < 8; ++i) {
            const int kt = 24 + i;
            short8 af = mk_afT(pw[2 * i], pw[2 * i + 1]);
            aZ  = __builtin_amdgcn_mfma_f32_16x16x32_bf16(af, ldsw[((0 * 32 + kt) << 6) + l], aZ, 0, 0, 0);
            aR  = __builtin_amdgcn_mfma_f32_16x16x32_bf16(af, ldsw[((1 * 32 + kt) << 6) + l], aR, 0, 0, 0);
            aG2 = __builtin_amdgcn_mfma_f32_16x16x32_bf16(af, ldsw[((2 * 32 + kt) << 6) + l], aG2, 0, 0, 0);
          }
        }
        if (l == 0) STG4(myfb, (unsigned)q);     // validated h1(q-2)
#pragma unroll
        for (int r = 0; r < 4; ++r) {
          red[(((par * 2 + mh) * 3 + 0) * 4 + r) * 64 + l] = aZ[r];
          red[(((par * 2 + mh) * 3 + 1) * 4 + r) * 64 + l] = aR[r];
          red[(((par * 2 + mh) * 3 + 2) * 4 + r) * 64 + l] = aG2[r];
        }
      } else {
        LDGU(gfb, f1b + l);                      // guard pre-loads
        LDGU(gfy, fyf + (l & 15));
        const unsigned int* b0 = pub0 + (size_t)((q - 1) & 3) * SLOT_W + bA * 512 + lg * 8;
        chunk_wait(b0, 0, (unsigned)q, pw);
#pragma unroll
        for (int kt = 0; kt < 8; ++kt) {
          short8 af = mk_afT(pw[2 * kt], pw[2 * kt + 1]);
          aZ  = __builtin_amdgcn_mfma_f32_16x16x32_bf16(af, ldsw[((0 * 32 + kt) << 6) + l], aZ, 0, 0, 0);
          aR  = __builtin_amdgcn_mfma_f32_16x16x32_bf16(af, ldsw[((1 * 32 + kt) << 6) + l], aR, 0, 0, 0);
          aG1 = __builtin_amdgcn_mfma_f32_16x16x32_bf16(af, ldsw[((2 * 32 + kt) << 6) + l], aG1, 0, 0, 0);
        }
        chunk_wait(b0, 8, (unsigned)q, pw);
#pragma unroll
        for (int i = 0; i < 8; ++i) {
          const int kt = 8 + i;
          short8 af = mk_afT(pw[2 * i], pw[2 * i + 1]);
          aZ  = __builtin_amdgcn_mfma_f32_16x16x32_bf16(af, ldsw[((0 * 32 + kt) << 6) + l], aZ, 0, 0, 0);
          aR  = __builtin_amdgcn_mfma_f32_16x16x32_bf16(af, ldsw[((1 * 32 + kt) << 6) + l], aR, 0, 0, 0);
          aG1 = __builtin_amdgcn_mfma_f32_16x16x32_bf16(af, ldsw[((2 * 32 + kt) << 6) + l], aG1, 0, 0, 0);
        }
        if (l == 0) STG4(myfa, (unsigned)q);     // validated h0(q-1)
      }
      __syncthreads();                           // red(par) ready (parity dbuf)
      if (kh == 0) {
        // overwrite guard: pub1 slot (q-1)&3 clobbers h1(q-5); readers at q-3
        if (q >= 4) {
          const unsigned thr = (unsigned)(q - 3);
          for (;;) {
            bool ok = ((l < 64 ? gfb : 0xFFFFFFFFu) >= thr) & ((gfy >= thr) | (0));
            if (__all((int)(((gfb >= thr)) & (gfy >= thr)))) break;
            __builtin_amdgcn_s_sleep(2);
            LDGU(gfb, f1b + l);
            LDGU(gfy, fyf + (l & 15));
            VDRAIN();
            (void)ok;
          }
        }
        unsigned int* po = pub1 + (size_t)((q - 1) & 3) * SLOT_W + u0 + lr;
        const unsigned tagO = (unsigned)q;
#pragma unroll
        for (int r = 0; r < 4; ++r) {
          const float z2 = red[(((par * 2 + mh) * 3 + 0) * 4 + r) * 64 + l];
          const float r2 = red[(((par * 2 + mh) * 3 + 1) * 4 + r) * 64 + l];
          const float g2 = red[(((par * 2 + mh) * 3 + 2) * 4 + r) * 64 + l];
          const float zz = sigm(aZ[r] + z2 + bz);
          const float rr = sigm(aR[r] + r2 + br);
          const float gg = tanhc(aG1[r] + bg + rr * g2);
          const float hn = gg + zz * (hm[r] - gg);
          hm[r] = hn;
          STG4(po + (size_t)(bC + r) * 512, ((unsigned)(unsigned short)f2bf(hn) << 16) | tagO);
          if (q == SS)
            out[(size_t)(BB * SS * OO) + (size_t)(bC + r) * (2 * HH) + HH + u0 + lr] = hn;
        }
      }
    }
  } else {
    // Y: y(p-2) = h1(p-2) @ wy^T + by. Off the critical cycle.
    const int mh  = wv & 1;
    const int ynt = wv >> 1;
    const int bA  = mh * 16 + lr;
    const int bC  = mh * 16 + lg * 4;
    const int yb  = bid - N0 - N1;
    const int oy  = yb * 32;
    const float byv = by[oy + ynt * 16 + lr];
    unsigned int* myfy = fyf + yb * 4 + wv;
    u32x4 pw[16];

    for (int p = 2; p <= SS + 1; ++p) {
      const unsigned int* bV = pub1 + (size_t)((p - 2) & 3) * SLOT_W + bA * 512 + lg * 8;
      f32x4 acc = {0.f, 0.f, 0.f, 0.f};
      chunk_wait(bV, 0, (unsigned)(p - 1), pw);
#pragma unroll
      for (int kt = 0; kt < 8; ++kt)
        acc = __builtin_amdgcn_mfma_f32_16x16x32_bf16(mk_afT(pw[2 * kt], pw[2 * kt + 1]),
                                                      ldsw[((ynt * 16 + kt) << 6) + l], acc, 0, 0, 0);
      chunk_wait(bV, 8, (unsigned)(p - 1), pw);
#pragma unroll
      for (int i = 0; i < 8; ++i)
        acc = __builtin_amdgcn_mfma_f32_16x16x32_bf16(mk_afT(pw[2 * i], pw[2 * i + 1]),
                                                      ldsw[((ynt * 16 + 8 + i) << 6) + l], acc, 0, 0, 0);
      if (l == 0) STG4(myfy, (unsigned)p);       // validated h1(p-2)
#pragma unroll
      for (int r = 0; r < 4; ++r)
        out[(size_t)(bC + r) * (SS * OO) + (size_t)(p - 2) * OO + oy + ynt * 16 + lr] = acc[r] + byv;
    }
  }
}

extern "C" void kernel_launch(void* const* d_in, const int* in_sizes, int n_in,
                              void* d_out, int out_size, void* d_ws, size_t ws_size,
                              hipStream_t stream) {
  (void)in_sizes; (void)n_in; (void)out_size; (void)ws_size;
  const float* x   = (const float*)d_in[0];
  const float* wx0 = (const float*)d_in[1];
  const float* bx0 = (const float*)d_in[2];
  const float* wh0 = (const float*)d_in[3];
  const float* wx1 = (const float*)d_in[4];
  const float* bx1 = (const float*)d_in[5];
  const float* wh1 = (const float*)d_in[6];
  const float* wy  = (const float*)d_in[7];
  const float* by  = (const float*)d_in[8];
  float* out = (float*)d_out;

  // zero flags + pub buffers -> every graph replay starts from identical state.
  hipMemsetAsync(d_ws, 0, WS_BYTES, stream);
  gru_persist<<<dim3(NBLK), dim3(THREADS), LDS_BYTES, stream>>>(
      x, wx0, bx0, wh0, wx1, bx1, wh1, wy, by, out, (unsigned char*)d_ws);
}